// Round 1
// baseline (63.388 us; speedup 1.0000x reference)
//
#include <hip/hip_runtime.h>

#define B_ 256
#define M_ 512
#define N_ 256
#define K_ 16
#define ROWS 256        // rows per pass-1 block
#define NC 32           // n-chunk staged per iteration
#define XPAD 36         // padded LDS row stride (floats), 16B-aligned, breaks bank alias

// ---------------- Pass 1 ----------------
// grid = B_ * (M_/ROWS) = 512 blocks, 256 threads.
// Each thread owns one row m: computes xv[b,m,0..15] and l[b,m]=x.w+bias.
// Block then tree-reduces acc over its 256 rows -> svpart[b][chunk][k].
__global__ __launch_bounds__(256) void fm_pass1(
    const float* __restrict__ x, const float* __restrict__ w,
    const float* __restrict__ bias, const float* __restrict__ v,
    float* __restrict__ xv, float* __restrict__ svpart, float* __restrict__ out)
{
    __shared__ __align__(16) float vL[N_][K_];   // 16 KiB
    __shared__ __align__(16) float wL[N_];       // 1 KiB
    __shared__ __align__(16) float xT[ROWS][XPAD]; // 36 KiB (reused for reduction)

    const int t = threadIdx.x;
    const int blk = blockIdx.x;
    const int b = blk >> 1;          // M_/ROWS == 2
    const int chunk = blk & 1;
    const int m0 = chunk * ROWS;

    // stage v (4096 floats) and w (256 floats)
    {
        const float4* v4 = (const float4*)v;
        float4* vL4 = (float4*)&vL[0][0];
        #pragma unroll
        for (int i = 0; i < 4; ++i) vL4[t + 256 * i] = v4[t + 256 * i];
        wL[t] = w[t];
    }

    const float* xb = x + ((size_t)b * M_ + m0) * N_;

    float acc[K_];
    #pragma unroll
    for (int k = 0; k < K_; ++k) acc[k] = 0.f;
    float lacc = 0.f;

    // staging: thread t loads row (t>>3)+32*i, 16B segment (t&7)*4 of current chunk
    const int lrow = t >> 3;
    const int lcol = (t & 7) * 4;
    float4 st[8];

    #pragma unroll
    for (int i = 0; i < 8; ++i)
        st[i] = *(const float4*)(xb + (size_t)(lrow + 32 * i) * N_ + 0 * NC + lcol);

    for (int nc = 0; nc < N_ / NC; ++nc) {
        __syncthreads();
        #pragma unroll
        for (int i = 0; i < 8; ++i)
            *(float4*)&xT[lrow + 32 * i][lcol] = st[i];
        __syncthreads();

        if (nc + 1 < N_ / NC) {
            #pragma unroll
            for (int i = 0; i < 8; ++i)
                st[i] = *(const float4*)(xb + (size_t)(lrow + 32 * i) * N_ + (nc + 1) * NC + lcol);
        }

        // compute this 32-n chunk for own row t
        #pragma unroll
        for (int n4 = 0; n4 < NC / 4; ++n4) {
            float4 xq = *(const float4*)&xT[t][n4 * 4];
            #pragma unroll
            for (int j = 0; j < 4; ++j) {
                const int n = nc * NC + n4 * 4 + j;
                const float xs = (j == 0) ? xq.x : (j == 1) ? xq.y : (j == 2) ? xq.z : xq.w;
                const float4* vrow = (const float4*)&vL[n][0];
                float4 v0 = vrow[0], v1 = vrow[1], v2 = vrow[2], v3 = vrow[3];
                acc[0]  += xs * v0.x; acc[1]  += xs * v0.y; acc[2]  += xs * v0.z; acc[3]  += xs * v0.w;
                acc[4]  += xs * v1.x; acc[5]  += xs * v1.y; acc[6]  += xs * v1.z; acc[7]  += xs * v1.w;
                acc[8]  += xs * v2.x; acc[9]  += xs * v2.y; acc[10] += xs * v2.z; acc[11] += xs * v2.w;
                acc[12] += xs * v3.x; acc[13] += xs * v3.y; acc[14] += xs * v3.z; acc[15] += xs * v3.w;
                lacc    += xs * wL[n];
            }
        }
    }

    // write xv row (64B contiguous per thread) and l -> out
    {
        float4* xvp = (float4*)(xv + ((size_t)b * M_ + m0 + t) * K_);
        xvp[0] = float4{acc[0],  acc[1],  acc[2],  acc[3]};
        xvp[1] = float4{acc[4],  acc[5],  acc[6],  acc[7]};
        xvp[2] = float4{acc[8],  acc[9],  acc[10], acc[11]};
        xvp[3] = float4{acc[12], acc[13], acc[14], acc[15]};
        out[(size_t)b * M_ + m0 + t] = lacc + bias[0];
    }

    // block reduction of acc over 256 rows -> svpart[b][chunk][0..15]
    __syncthreads();                         // everyone done reading xT
    float4* red = (float4*)&xT[0][0];        // [256][4] float4 view (4096 floats)
    #pragma unroll
    for (int q = 0; q < 4; ++q)
        red[t * 4 + q] = float4{acc[q * 4 + 0], acc[q * 4 + 1], acc[q * 4 + 2], acc[q * 4 + 3]};
    __syncthreads();
    for (int s = 128; s > 0; s >>= 1) {
        if (t < s) {
            #pragma unroll
            for (int q = 0; q < 4; ++q) {
                float4 a = red[t * 4 + q], c = red[(t + s) * 4 + q];
                red[t * 4 + q] = float4{a.x + c.x, a.y + c.y, a.z + c.z, a.w + c.w};
            }
        }
        __syncthreads();
    }
    if (t < 16) svpart[(size_t)(b * 2 + chunk) * 16 + t] = ((float*)red)[t];
}

// ---------------- Pass 2 ----------------
// grid = B_ * 2, 256 threads; thread per row.
// out[b,m] += 0.5 * (xv[b,m,:].sv[b,:] - ||xv[b,m,:]||^2)
__global__ __launch_bounds__(256) void fm_pass2(
    const float* __restrict__ xv, const float* __restrict__ svpart,
    float* __restrict__ out)
{
    const int t = threadIdx.x;
    const int blk = blockIdx.x;
    const int b = blk >> 1;
    const int m = (blk & 1) * ROWS + t;
    __shared__ __align__(16) float svL[16];
    if (t < 16)
        svL[t] = svpart[(size_t)(b * 2 + 0) * 16 + t] + svpart[(size_t)(b * 2 + 1) * 16 + t];
    __syncthreads();

    const float4* xvp = (const float4*)(xv + ((size_t)b * M_ + m) * K_);
    float4 a0 = xvp[0], a1 = xvp[1], a2 = xvp[2], a3 = xvp[3];
    const float4* s4 = (const float4*)svL;
    float4 s0 = s4[0], s1 = s4[1], s2 = s4[2], s3 = s4[3];

    float rs = a0.x * s0.x + a0.y * s0.y + a0.z * s0.z + a0.w * s0.w
             + a1.x * s1.x + a1.y * s1.y + a1.z * s1.z + a1.w * s1.w
             + a2.x * s2.x + a2.y * s2.y + a2.z * s2.z + a2.w * s2.w
             + a3.x * s3.x + a3.y * s3.y + a3.z * s3.z + a3.w * s3.w;
    float dg = a0.x * a0.x + a0.y * a0.y + a0.z * a0.z + a0.w * a0.w
             + a1.x * a1.x + a1.y * a1.y + a1.z * a1.z + a1.w * a1.w
             + a2.x * a2.x + a2.y * a2.y + a2.z * a2.z + a2.w * a2.w
             + a3.x * a3.x + a3.y * a3.y + a3.z * a3.z + a3.w * a3.w;

    const size_t o = (size_t)b * M_ + m;
    out[o] = out[o] + 0.5f * (rs - dg);
}

extern "C" void kernel_launch(void* const* d_in, const int* in_sizes, int n_in,
                              void* d_out, int out_size, void* d_ws, size_t ws_size,
                              hipStream_t stream) {
    const float* x    = (const float*)d_in[0];
    const float* w    = (const float*)d_in[1];
    const float* bias = (const float*)d_in[2];
    const float* v    = (const float*)d_in[3];
    float* out = (float*)d_out;

    float* xv     = (float*)d_ws;                         // B*M*K floats = 8 MiB
    float* svpart = xv + (size_t)B_ * M_ * K_;            // B*2*16 floats = 32 KiB

    fm_pass1<<<dim3(B_ * (M_ / ROWS)), dim3(256), 0, stream>>>(x, w, bias, v, xv, svpart, out);
    fm_pass2<<<dim3(B_ * 2), dim3(256), 0, stream>>>(xv, svpart, out);
}